// Round 13
// baseline (525.986 us; speedup 1.0000x reference)
//
#include <hip/hip_runtime.h>

typedef unsigned short u16;
typedef unsigned int u32;
typedef __bf16 bf16x8 __attribute__((ext_vector_type(8)));
typedef float f32x4 __attribute__((ext_vector_type(4)));
typedef u16 u16x4 __attribute__((ext_vector_type(4)));
typedef u16 u16x8 __attribute__((ext_vector_type(8)));
typedef u32 u32x2 __attribute__((ext_vector_type(2)));

#define SCL2E 0.12751744898229718f   // (1/sqrt(128)) * log2(e), folded into Q-proj

__device__ __forceinline__ u16 f2bf(float f) {
  union { float f; u32 u; } x; x.f = f;
  u32 r = x.u + 0x7fffu + ((x.u >> 16) & 1u);   // RNE
  return (u16)(r >> 16);
}

__device__ __forceinline__ u32 cvt_pk_bf16(float lo, float hi) {
  u32 r;
  asm("v_cvt_pk_bf16_f32 %0, %1, %2" : "=v"(r) : "v"(lo), "v"(hi));
  return r;
}

__device__ __forceinline__ void gld16(const void* g, void* l) {
  __builtin_amdgcn_global_load_lds(
      (const __attribute__((address_space(1))) u32*)g,
      (__attribute__((address_space(3))) u32*)l, 16, 0, 0);
}

#define SBAR() __builtin_amdgcn_s_barrier()
#define SCHEDB() __builtin_amdgcn_sched_barrier(0)
#define WAITVM(N) do { asm volatile("s_waitcnt vmcnt(" #N ")" ::: "memory"); \
                       __builtin_amdgcn_sched_barrier(0); } while (0)

// stage one 64-row round (1 gld_lds/thread): tile rows RIT..RIT+63, k-cols KT*64..+63
#define STG(G, R0, DST, RIT, KT, K) do { \
    int rit_ = (RIT) + w*8 + lr; \
    int ch_ = lch ^ (rit_ & 7); \
    gld16((G) + ((R0) + rit_) * (long)(K) + (long)(KT)*64 + ch_*8, \
          (DST) + ((RIT) + w*8)*64); } while (0)

// ---------------- fp32 -> bf16 convert: ALL 7 tensors in one dispatch ----------------
__device__ __forceinline__ void cvt_body(const float* __restrict__ in,
                                         u16* __restrict__ out, int n8) {
  int stride = gridDim.x * 256;
  for (int i = blockIdx.x * 256 + threadIdx.x; i < n8; i += stride) {
    float4 a = ((const float4*)in)[2*i];
    float4 b = ((const float4*)in)[2*i+1];
    u16x8 o;
    o[0]=f2bf(a.x); o[1]=f2bf(a.y); o[2]=f2bf(a.z); o[3]=f2bf(a.w);
    o[4]=f2bf(b.x); o[5]=f2bf(b.y); o[6]=f2bf(b.z); o[7]=f2bf(b.w);
    ((u16x8*)out)[i] = o;
  }
}

__global__ __launch_bounds__(256) void cvt7(
    const float* __restrict__ s0, const float* __restrict__ s1,
    const float* __restrict__ s2, const float* __restrict__ s3,
    const float* __restrict__ s4, const float* __restrict__ s5,
    const float* __restrict__ s6,
    u16* __restrict__ d0, u16* __restrict__ d1, u16* __restrict__ d2,
    u16* __restrict__ d3, u16* __restrict__ d4, u16* __restrict__ d5,
    u16* __restrict__ d6) {
  const float* src; u16* dst; int n8;
  switch (blockIdx.y) {
    case 0: src = s0; dst = d0; n8 = 2097152; break;
    case 1: src = s1; dst = d1; n8 = 2097152; break;
    case 2: src = s2; dst = d2; n8 = 2097152; break;
    case 3: src = s3; dst = d3; n8 = 2097152; break;
    case 4: src = s4; dst = d4; n8 = 2097152; break;
    case 5: src = s5; dst = d5; n8 = 524288;  break;
    default: src = s6; dst = d6; n8 = 524288; break;
  }
  cvt_body(src, dst, n8);
}

#define MFMA_(A, B, C) __builtin_amdgcn_mfma_f32_16x16x32_bf16(A, B, C, 0, 0, 0)

// ---------------- 256x256 bf16 GEMM: ONE barrier per K-tile (r10/r12-validated) -----
// 512 thr = 8 waves (2M x 4N), per-wave 128x64, BK=64. A dbuf (64K), B tribuf (96K).
// No intra-tile barriers -> waves de-sync, LDS reads overlap MFMA via TLP.
// COUNTED tile-end WAITVM(4) (T4): leaves B(kt+2)x4 in flight ACROSS the barrier.
// HAZARD SEAL (FIFO-traced r10, replay-clean r10/r12).
template<int OUTF32>
__device__ __forceinline__ void gemm256_body(
    const u16* __restrict__ Ag, const u16* __restrict__ Bg, void* __restrict__ Cp,
    const int K, const int ldc, const long m0, const long n0, const long cb,
    const float escale, u16* __restrict__ As, u16* __restrict__ Bs) {
  const int lane = threadIdx.x & 63, w = threadIdx.x >> 6;
  const int wm = w >> 2, wn = w & 3;
  const int c = lane & 15, grp = lane >> 4;
  const int lr = lane >> 3, lch = lane & 7;

  f32x4 acc[8][4] = {};
  const int NK = K >> 6;   // requires NK >= 3

  // prologue: B(0)x4, A(0)x4, B(1)x4 -> 12 in flight; WAITVM(4) drains B0+A0
  STG(Bg, n0, Bs, 0, 0, K);   STG(Bg, n0, Bs, 64, 0, K);
  STG(Bg, n0, Bs, 128, 0, K); STG(Bg, n0, Bs, 192, 0, K);
  STG(Ag, m0, As, 0, 0, K);   STG(Ag, m0, As, 64, 0, K);
  STG(Ag, m0, As, 128, 0, K); STG(Ag, m0, As, 192, 0, K);
  {
    u16* B1 = Bs + 16384;
    STG(Bg, n0, B1, 0, 1, K);   STG(Bg, n0, B1, 64, 1, K);
    STG(Bg, n0, B1, 128, 1, K); STG(Bg, n0, B1, 192, 1, K);
  }
  WAITVM(4);   // leaves [B(1)x4] — the loop invariant
  SBAR();

  for (int kt = 0; kt < NK; ++kt) {
    const u16* At = As + (kt & 1) * 16384;
    u16* An = As + ((kt & 1) ^ 1) * 16384;
    const u16* Bt = Bs + (kt % 3) * 16384;
    u16* Bn = Bs + ((kt + 2) % 3) * 16384;
    const bool am = (kt + 1 < NK), bm = (kt + 2 < NK);

    bf16x8 a0, a1, a2, a3, bfr[4];
#define LDAF(mi, ks) (*(const bf16x8*)(At + (wm*128 + (mi)*16 + c)*64 + ((((ks)*4 + grp)) ^ (c & 7))*8))
#define LDBF(ni, ks) (*(const bf16x8*)(Bt + (wn*64  + (ni)*16 + c)*64 + ((((ks)*4 + grp)) ^ (c & 7))*8))
#define MFMA16(MB) do { \
    __builtin_amdgcn_s_setprio(1); \
    _Pragma("unroll") \
    for (int ni = 0; ni < 4; ++ni) { \
      acc[(MB)+0][ni] = MFMA_(a0, bfr[ni], acc[(MB)+0][ni]); \
      acc[(MB)+1][ni] = MFMA_(a1, bfr[ni], acc[(MB)+1][ni]); \
      acc[(MB)+2][ni] = MFMA_(a2, bfr[ni], acc[(MB)+2][ni]); \
      acc[(MB)+3][ni] = MFMA_(a3, bfr[ni], acc[(MB)+3][ni]); \
    } \
    __builtin_amdgcn_s_setprio(0); } while (0)

    // phi0: mi0-3 x ks0  (+ stage A(kt+1) all 4 rounds)
    a0 = LDAF(0,0); a1 = LDAF(1,0); a2 = LDAF(2,0); a3 = LDAF(3,0);
    bfr[0] = LDBF(0,0); bfr[1] = LDBF(1,0); bfr[2] = LDBF(2,0); bfr[3] = LDBF(3,0);
    if (am) { STG(Ag, m0, An, 0, kt+1, K); STG(Ag, m0, An, 64, kt+1, K);
              STG(Ag, m0, An, 128, kt+1, K); STG(Ag, m0, An, 192, kt+1, K); }
    MFMA16(0);
    SCHEDB();
    // phi1: mi4-7 x ks0  (+ stage B(kt+2) r0,r64)
    a0 = LDAF(4,0); a1 = LDAF(5,0); a2 = LDAF(6,0); a3 = LDAF(7,0);
    if (bm) { STG(Bg, n0, Bn, 0, kt+2, K); STG(Bg, n0, Bn, 64, kt+2, K); }
    MFMA16(4);
    SCHEDB();
    // phi2: mi0-3 x ks1  (+ stage B(kt+2) r128,r192)
    a0 = LDAF(0,1); a1 = LDAF(1,1); a2 = LDAF(2,1); a3 = LDAF(3,1);
    bfr[0] = LDBF(0,1); bfr[1] = LDBF(1,1); bfr[2] = LDBF(2,1); bfr[3] = LDBF(3,1);
    if (bm) { STG(Bg, n0, Bn, 128, kt+2, K); STG(Bg, n0, Bn, 192, kt+2, K); }
    MFMA16(0);
    SCHEDB();
    // phi3: mi4-7 x ks1
    a0 = LDAF(4,1); a1 = LDAF(5,1); a2 = LDAF(6,1); a3 = LDAF(7,1);
    MFMA16(4);
    // tile boundary: counted drain (leaves B(kt+2)x4 in flight), single rendezvous
    if (bm) { WAITVM(4); } else { WAITVM(0); }
    SBAR();
    SCHEDB();
#undef MFMA16
#undef LDAF
#undef LDBF
  }

  // epilogue: C/D layout col = lane&15, row = (lane>>4)*4 + reg  [m89/m91]
  #pragma unroll
  for (int mi = 0; mi < 8; ++mi) {
    #pragma unroll
    for (int rr = 0; rr < 4; ++rr) {
      long row = m0 + wm*128 + mi*16 + grp*4 + rr;
      #pragma unroll
      for (int ni = 0; ni < 4; ++ni) {
        long col = cb + wn*64 + ni*16 + c;
        if (OUTF32) ((float*)Cp)[row*ldc + col] = acc[mi][ni][rr];
        else        ((u16*)Cp)[row*ldc + col]  = f2bf(acc[mi][ni][rr] * escale);
      }
    }
  }
}

// ---------------- 128x256 bf16 GEMM (KV half-job): r10 schedule + fused V^T out -----
// 8 waves (2M x 4N), per-wave 64x64, BK=64. A TRIBUF (48KB), B TRIBUF (96KB).
// Counted WAITVM(6)/tile. VOUT=0: K-proj -> KVp[4096][1024]. VOUT=1: V-proj ->
// Vt[b][feat][s] transposed directly (u16x4; rr spans 4 consecutive s).
template<int VOUT>
__device__ __forceinline__ void gemm128_body(
    const u16* __restrict__ Ag, const u16* __restrict__ Bg, u16* __restrict__ Cp,
    u16* __restrict__ Vt, const int K, const int ldc, const long m0, const long n0,
    const long cb, u16* __restrict__ As, u16* __restrict__ Bs) {
  const int lane = threadIdx.x & 63, w = threadIdx.x >> 6;
  const int wm = w >> 2, wn = w & 3;
  const int c = lane & 15, grp = lane >> 4;
  const int lr = lane >> 3, lch = lane & 7;

  f32x4 acc[4][4] = {};
  const int NK = K >> 6;   // requires NK >= 3

  // prologue: B(0)x4, A(0)x2, B(1)x4, A(1)x2 -> 12; WAITVM(6) drains B0+A0
  STG(Bg, n0, Bs, 0, 0, K);   STG(Bg, n0, Bs, 64, 0, K);
  STG(Bg, n0, Bs, 128, 0, K); STG(Bg, n0, Bs, 192, 0, K);
  STG(Ag, m0, As, 0, 0, K);   STG(Ag, m0, As, 64, 0, K);
  {
    u16* B1 = Bs + 16384; u16* A1 = As + 8192;
    STG(Bg, n0, B1, 0, 1, K);   STG(Bg, n0, B1, 64, 1, K);
    STG(Bg, n0, B1, 128, 1, K); STG(Bg, n0, B1, 192, 1, K);
    STG(Ag, m0, A1, 0, 1, K);   STG(Ag, m0, A1, 64, 1, K);
  }
  WAITVM(6);   // leaves [B(1)x4, A(1)x2] — the loop invariant
  SBAR();

  for (int kt = 0; kt < NK; ++kt) {
    const u16* At = As + (kt % 3) * 8192;
    const u16* Bt = Bs + (kt % 3) * 16384;
    u16* An = As + ((kt + 2) % 3) * 8192;
    u16* Bn = Bs + ((kt + 2) % 3) * 16384;
    const bool bm = (kt + 2 < NK);

    bf16x8 a0, a1, a2, a3, bfr[4];
#define LDAF(mi, ks) (*(const bf16x8*)(At + (wm*64 + (mi)*16 + c)*64 + ((((ks)*4 + grp)) ^ (c & 7))*8))
#define LDBF(ni, ks) (*(const bf16x8*)(Bt + (wn*64 + (ni)*16 + c)*64 + ((((ks)*4 + grp)) ^ (c & 7))*8))
#define MFMA16K() do { \
    __builtin_amdgcn_s_setprio(1); \
    _Pragma("unroll") \
    for (int ni = 0; ni < 4; ++ni) { \
      acc[0][ni] = MFMA_(a0, bfr[ni], acc[0][ni]); \
      acc[1][ni] = MFMA_(a1, bfr[ni], acc[1][ni]); \
      acc[2][ni] = MFMA_(a2, bfr[ni], acc[2][ni]); \
      acc[3][ni] = MFMA_(a3, bfr[ni], acc[3][ni]); \
    } \
    __builtin_amdgcn_s_setprio(0); } while (0)

    // phi0: ks0  (+ stage B(kt+2) r0,r64)
    a0 = LDAF(0,0); a1 = LDAF(1,0); a2 = LDAF(2,0); a3 = LDAF(3,0);
    bfr[0] = LDBF(0,0); bfr[1] = LDBF(1,0); bfr[2] = LDBF(2,0); bfr[3] = LDBF(3,0);
    if (bm) { STG(Bg, n0, Bn, 0, kt+2, K); STG(Bg, n0, Bn, 64, kt+2, K); }
    MFMA16K();
    SCHEDB();
    // phi1: ks1  (+ stage B(kt+2) r128,r192 + A(kt+2) x2)
    a0 = LDAF(0,1); a1 = LDAF(1,1); a2 = LDAF(2,1); a3 = LDAF(3,1);
    bfr[0] = LDBF(0,1); bfr[1] = LDBF(1,1); bfr[2] = LDBF(2,1); bfr[3] = LDBF(3,1);
    if (bm) { STG(Bg, n0, Bn, 128, kt+2, K); STG(Bg, n0, Bn, 192, kt+2, K);
              STG(Ag, m0, An, 0, kt+2, K); STG(Ag, m0, An, 64, kt+2, K); }
    MFMA16K();
    if (bm) { WAITVM(6); } else { WAITVM(0); }
    SBAR();
    SCHEDB();
#undef MFMA16K
#undef LDAF
#undef LDBF
  }

  if (VOUT == 0) {
    #pragma unroll
    for (int mi = 0; mi < 4; ++mi) {
      #pragma unroll
      for (int rr = 0; rr < 4; ++rr) {
        long row = m0 + wm*64 + mi*16 + grp*4 + rr;
        #pragma unroll
        for (int ni = 0; ni < 4; ++ni) {
          long col = cb + wn*64 + ni*16 + c;
          Cp[row*ldc + col] = f2bf(acc[mi][ni][rr]);
        }
      }
    }
  } else {
    // transposed write: Vt[b][feat][s], 4 consecutive s per u16x4 store
    #pragma unroll
    for (int mi = 0; mi < 4; ++mi) {
      long s_glob = m0 + wm*64 + mi*16 + grp*4;
      long bb = s_glob >> 11;
      long s_loc = s_glob & 2047;
      #pragma unroll
      for (int ni = 0; ni < 4; ++ni) {
        long feat = cb + wn*64 + ni*16 + c;
        u16x4 o4;
        #pragma unroll
        for (int rr = 0; rr < 4; ++rr) o4[rr] = f2bf(acc[mi][ni][rr]);
        *(u16x4*)(Vt + (bb*1024 + feat)*2048 + s_loc) = o4;
      }
    }
  }
}

// Q projection: 256 blocks, one 256^2 tile each (measurement split r13)
__global__ __launch_bounds__(512, 2) void q_proj(
    const u16* __restrict__ qb, const u16* __restrict__ wqb, u16* __restrict__ Qp) {
  __shared__ __attribute__((aligned(16))) u16 SMEM[81920];   // 160 KiB
  int wg = ((int)blockIdx.x & 7) * 32 + ((int)blockIdx.x >> 3);  // XCD swizzle
  gemm256_body<0>(qb, wqb, Qp, 4096, 4096,
                  (long)(wg >> 4) * 256, (long)(wg & 15) * 256, (long)(wg & 15) * 256,
                  SCL2E, SMEM, SMEM + 32768);
}

// K/V projections: 256 blocks, one 128x256 half-job each
__global__ __launch_bounds__(512, 2) void kv_proj(
    const u16* __restrict__ kb, const u16* __restrict__ vb,
    const u16* __restrict__ wkv, u16* __restrict__ KVp, u16* __restrict__ Vt) {
  __shared__ __attribute__((aligned(16))) u16 SMEM[73728];   // 144 KiB
  int wg = ((int)blockIdx.x & 7) * 32 + ((int)blockIdx.x >> 3);  // XCD swizzle
  int mt = wg >> 3, nt = wg & 7;
  long n0 = (long)(nt & 3) * 256;
  if (nt < 4)
    gemm128_body<0>(kb, wkv, KVp, nullptr, 4096, 1024, (long)mt * 128, n0, n0,
                    SMEM, SMEM + 24576);
  else
    gemm128_body<1>(vb, wkv + 4194304, nullptr, Vt, 4096, 0, (long)mt * 128, n0, n0,
                    SMEM, SMEM + 24576);
}

__global__ __launch_bounds__(512, 2) void gemm_out(
    const u16* __restrict__ A, const u16* __restrict__ Bw, float* __restrict__ C) {
  __shared__ __attribute__((aligned(16))) u16 SMEM[81920];   // 160 KiB
  int wg = ((int)blockIdx.x & 7) * 32 + ((int)blockIdx.x >> 3);  // 256%8==0
  long m0 = (long)(wg >> 4) * 256, n0 = (long)(wg & 15) * 256;
  gemm256_body<1>(A, Bw, C, 4096, 4096, m0, n0, n0, 1.f, SMEM, SMEM + 32768);
}

// ---------------- causal flash attention (r7-validated; KVp stride 1024) ----------
// 512-thread / 8-wave blocks, 256-row Q-tiles, paired (x, 7-x) -> 256 uniform
// blocks = exactly 1 round, 8 waves/CU. K and V^T in double-buffered swizzled
// LDS (96 KiB). Swapped QK^T softmax; per-wave P through LDS; wave-uniform
// early-out on fully-masked KV tiles.
__global__ __launch_bounds__(512, 2) void attn_fwd(
    const u16* __restrict__ Qp, const u16* __restrict__ KVp,
    const u16* __restrict__ Vt, u16* __restrict__ AO) {
  const int head = blockIdx.y, b = blockIdx.z;
  const int g = head >> 2;
  const int tid = threadIdx.x, lane = tid & 63, w = tid >> 6;
  const int c = lane & 15, grp = lane >> 4;

  __shared__ __attribute__((aligned(16))) u16 Ks[2][64*128];
  __shared__ __attribute__((aligned(16))) u16 Vts[2][128*64];
  __shared__ __attribute__((aligned(16))) u16 Ps[8][32*64];
  u16* __restrict__ pw = &Ps[w][0];

  for (int half = 0; half < 2; ++half) {
    const int qt = half ? (7 - (int)blockIdx.x) : (int)blockIdx.x;
    const int q0 = qt * 256;
    const int qw = q0 + w * 32;

    bf16x8 qf[2][4];   // Q[qw + h*16 + c][t*32 + grp*8 + j]
    #pragma unroll
    for (int h = 0; h < 2; ++h) {
      const u16* qb = Qp + (long)(b*2048 + qw + h*16 + c)*4096 + head*128 + grp*8;
      #pragma unroll
      for (int t = 0; t < 4; ++t) qf[h][t] = *(const bf16x8*)(qb + t*32);
    }

    float m_run[2] = {-1e30f, -1e30f}, l_run[2] = {0.f, 0.f};
    f32x4 oacc[2][8] = {};

    const int ntiles = 4*qt + 4;

    auto STAGE = [&](int buf, int kt) {
      const int kv0 = kt * 64;
      #pragma unroll
      for (int p = 0; p < 2; ++p) {
        int idx = p*512 + w*64 + lane;
        int krow = idx >> 4, kc = idx & 15;
        int kcs = kc ^ (krow & 7);            // pre-swizzled source -> swizzled LDS
        gld16(KVp + (long)(b*2048 + kv0 + krow)*1024 + g*128 + kcs*8,
              &Ks[buf][(p*512 + w*64)*8]);
        int d = idx >> 3, vc = idx & 7;
        int vcs = vc ^ (d & 7);
        gld16(Vt + (long)(b*1024 + g*128 + d)*2048 + kv0 + vcs*8,
              &Vts[buf][(p*512 + w*64)*8]);
      }
    };

    if (half) __syncthreads();   // LDS reuse guard between q-tiles
    STAGE(0, 0);
    int cur = 0;
    for (int kt = 0; kt < ntiles; ++kt) {
      const int kv0 = kt * 64;
      __syncthreads();   // implicit vmcnt(0)+lgkmcnt(0) drain: buf[cur] ready
      if (kt + 1 < ntiles) STAGE(cur ^ 1, kt + 1);

      if (kv0 <= qw + 31) {   // wave-uniform: skip fully-masked tiles
        const u16* __restrict__ Kc = &Ks[cur][0];
        const u16* __restrict__ Vc = &Vts[cur][0];

        // S^T = mfma(K, Q): lane holds S[q=qw+h*16+c][kv0 + f*16 + grp*4 + r]
        f32x4 sacc[2][4] = {};
        __builtin_amdgcn_s_setprio(1);
        #pragma unroll
        for (int f = 0; f < 4; ++f) {
          const int row = f*16 + c;
          #pragma unroll
          for (int t = 0; t < 4; ++t) {
            bf16x8 kf = *(const bf16x8*)(Kc + row*128 + (((t*4 + grp) ^ (c & 7)) * 8));
            sacc[0][f] = __builtin_amdgcn_mfma_f32_16x16x32_bf16(kf, qf[0][t], sacc[0][f], 0, 0, 0);
            sacc[1][f] = __builtin_amdgcn_mfma_f32_16x16x32_bf16(kf, qf[1][t], sacc[1][f], 0, 0, 0);
          }
        }
        __builtin_amdgcn_s_setprio(0);

        #pragma unroll
        for (int h = 0; h < 2; ++h) {
          const int qg = qw + h*16 + c;
          float sv[16];
          if (kv0 + 63 > qw + h*16) {          // boundary tile for this fragment
            #pragma unroll
            for (int f = 0; f < 4; ++f)
              #pragma unroll
              for (int r = 0; r < 4; ++r) {
                float x = sacc[h][f][r];
                if (kv0 + f*16 + grp*4 + r > qg) x = -1e30f;
                sv[f*4 + r] = x;
              }
          } else {
            #pragma unroll
            for (int f = 0; f < 4; ++f)
              #pragma unroll
              for (int r = 0; r < 4; ++r) sv[f*4 + r] = sacc[h][f][r];
          }
          float tm[8];
          #pragma unroll
          for (int i = 0; i < 8; ++i) tm[i] = fmaxf(sv[i], sv[i+8]);
          #pragma unroll
          for (int i = 0; i < 4; ++i) tm[i] = fmaxf(tm[i], tm[i+4]);
          float tmax = fmaxf(fmaxf(tm[0], tm[2]), fmaxf(tm[1], tm[3]));
          tmax = fmaxf(tmax, __shfl_xor(tmax, 16));
          tmax = fmaxf(tmax, __shfl_xor(tmax, 32));

          float m_new = m_run[h];
          if (!__all(tmax <= m_run[h] + 8.f)) {   // defer-max
            m_new = fmaxf(m_run[h], tmax);
            float corr = exp2f(m_run[h] - m_new);
            l_run[h] *= corr;
            #pragma unroll
            for (int n = 0; n < 8; ++n) oacc[h][n] *= corr;
            m_run[h] = m_new;
          }

          float tsum = 0.f;
          u32 pk[8];
          #pragma unroll
          for (int i = 0; i < 8; ++i) {
            float p0 = exp2f(sv[2*i]   - m_new);
            float p1 = exp2f(sv[2*i+1] - m_new);
            tsum += p0 + p1;
            pk[i] = cvt_pk_bf16(p0, p1);
          }
          tsum += __shfl_xor(tsum, 16);
          tsum += __shfl_xor(tsum, 32);
          l_run[h] += tsum;

          // P rows h*16+c, col swizzle ^= (q&7)<<3, packed b64 writes
          #pragma unroll
          for (int f = 0; f < 4; ++f) {
            int col = (f*16 + grp*4) ^ ((c & 7) << 3);
            u32x2 pv; pv[0] = pk[2*f]; pv[1] = pk[2*f + 1];
            *(u32x2*)(pw + (h*16 + c)*64 + col) = pv;
          }
        }

        // O^T += mfma(V^T, P^T): V fragment shared by both q-fragments
        __builtin_amdgcn_s_setprio(1);
        #pragma unroll
        for (int u = 0; u < 2; ++u) {
          const int pcol = (u*32 + grp*8) ^ ((c & 7) << 3);
          bf16x8 pf0 = *(const bf16x8*)(pw + c*64 + pcol);
          bf16x8 pf1 = *(const bf16x8*)(pw + (16 + c)*64 + pcol);
          #pragma unroll
          for (int n = 0; n < 8; ++n) {
            bf16x8 vf = *(const bf16x8*)(Vc + (n*16 + c)*64 + (((u*4 + grp) ^ (c & 7)) * 8));
            oacc[0][n] = __builtin_amdgcn_mfma_f32_16x16x32_bf16(vf, pf0, oacc[0][n], 0, 0, 0);
            oacc[1][n] = __builtin_amdgcn_mfma_f32_16x16x32_bf16(vf, pf1, oacc[1][n], 0, 0, 0);
          }
        }
        __builtin_amdgcn_s_setprio(0);
      }
      cur ^= 1;
    }

    #pragma unroll
    for (int h = 0; h < 2; ++h) {
      const float inv = 1.0f / l_run[h];
      u16* ob = AO + (long)(b*2048 + qw + h*16 + c)*4096 + head*128 + grp*4;
      #pragma unroll
      for (int n = 0; n < 8; ++n) {
        u32x2 o;
        o[0] = cvt_pk_bf16(oacc[h][n][0]*inv, oacc[h][n][1]*inv);
        o[1] = cvt_pk_bf16(oacc[h][n][2]*inv, oacc[h][n][3]*inv);
        *(u32x2*)(ob + n*16) = o;
      }
    }
  }
}

// ---------------- launcher ----------------
extern "C" void kernel_launch(void* const* d_in, const int* in_sizes, int n_in,
                              void* d_out, int out_size, void* d_ws, size_t ws_size,
                              hipStream_t stream) {
  const float* q   = (const float*)d_in[0];
  const float* k   = (const float*)d_in[1];
  const float* v   = (const float*)d_in[2];
  const float* w_q = (const float*)d_in[3];
  const float* w_k = (const float*)d_in[4];
  const float* w_v = (const float*)d_in[5];
  const float* w_o = (const float*)d_in[6];

  u16* ws  = (u16*)d_ws;
  u16* qb  = ws;                  // 16777216  q bf16
  u16* kb  = qb  + 16777216;      // 16777216  k bf16
  u16* vb  = kb  + 16777216;      // 16777216  v bf16
  u16* wqb = vb  + 16777216;      // 16777216  w_q bf16
  u16* wob = wqb + 16777216;      // 16777216  w_out bf16
  u16* wkv = wob + 16777216;      // 8388608   [w_k ; w_v] bf16
  u16* Qp  = wkv + 8388608;       // 16777216  query proj (pre-scaled by SCL2E)
  u16* KVp = Qp  + 16777216;      // 4194304   K proj [4096][1024]
  u16* Vtp = KVp + 4194304;       // 4194304   V^T [2][1024][2048] (direct from proj)
  u16* AO  = vb;                  // alias: vb dead after kv_proj
  (void)ws_size; (void)in_sizes; (void)n_in; (void)out_size;

  // all 7 f32->bf16 conversions, one dispatch
  cvt7<<<dim3(1024, 7), dim3(256), 0, stream>>>(
      q, k, v, w_q, w_o, w_k, w_v,
      qb, kb, vb, wqb, wob, wkv, wkv + 4194304);

  // projections (split for per-kernel counters; identical validated bodies)
  q_proj<<<256, dim3(512), 0, stream>>>(qb, wqb, Qp);
  kv_proj<<<256, dim3(512), 0, stream>>>(kb, vb, wkv, KVp, Vtp);
  // flash attention: 256 uniform 8-wave blocks (paired 256-row q-tiles)
  attn_fwd<<<dim3(4,32,2), dim3(512), 0, stream>>>(Qp, KVp, Vtp, AO);
  // out = AO @ w_out^T : f32 -> d_out (256 blocks)
  gemm_out<<<256, dim3(512), 0, stream>>>(AO, wob, (float*)d_out);
}

// Round 14
// 517.216 us; speedup vs baseline: 1.0170x; 1.0170x over previous
//
#include <hip/hip_runtime.h>

typedef unsigned short u16;
typedef unsigned int u32;
typedef __bf16 bf16x8 __attribute__((ext_vector_type(8)));
typedef float f32x4 __attribute__((ext_vector_type(4)));
typedef u16 u16x4 __attribute__((ext_vector_type(4)));
typedef u16 u16x8 __attribute__((ext_vector_type(8)));
typedef u32 u32x2 __attribute__((ext_vector_type(2)));

#define SCL2E 0.12751744898229718f   // (1/sqrt(128)) * log2(e), folded into Q-proj

__device__ __forceinline__ u16 f2bf(float f) {
  union { float f; u32 u; } x; x.f = f;
  u32 r = x.u + 0x7fffu + ((x.u >> 16) & 1u);   // RNE
  return (u16)(r >> 16);
}

__device__ __forceinline__ u32 cvt_pk_bf16(float lo, float hi) {
  u32 r;
  asm("v_cvt_pk_bf16_f32 %0, %1, %2" : "=v"(r) : "v"(lo), "v"(hi));
  return r;
}

__device__ __forceinline__ void gld16(const void* g, void* l) {
  __builtin_amdgcn_global_load_lds(
      (const __attribute__((address_space(1))) u32*)g,
      (__attribute__((address_space(3))) u32*)l, 16, 0, 0);
}

#define SBAR() __builtin_amdgcn_s_barrier()
#define SCHEDB() __builtin_amdgcn_sched_barrier(0)
#define WAITVM(N) do { asm volatile("s_waitcnt vmcnt(" #N ")" ::: "memory"); \
                       __builtin_amdgcn_sched_barrier(0); } while (0)

// stage one 64-row round (1 gld_lds/thread): tile rows RIT..RIT+63, k-cols KT*64..+63
#define STG(G, R0, DST, RIT, KT, K) do { \
    int rit_ = (RIT) + w*8 + lr; \
    int ch_ = lch ^ (rit_ & 7); \
    gld16((G) + ((R0) + rit_) * (long)(K) + (long)(KT)*64 + ch_*8, \
          (DST) + ((RIT) + w*8)*64); } while (0)

// ---------------- fp32 -> bf16 convert: ALL 7 tensors in one dispatch ----------------
__device__ __forceinline__ void cvt_body(const float* __restrict__ in,
                                         u16* __restrict__ out, int n8) {
  int stride = gridDim.x * 256;
  for (int i = blockIdx.x * 256 + threadIdx.x; i < n8; i += stride) {
    float4 a = ((const float4*)in)[2*i];
    float4 b = ((const float4*)in)[2*i+1];
    u16x8 o;
    o[0]=f2bf(a.x); o[1]=f2bf(a.y); o[2]=f2bf(a.z); o[3]=f2bf(a.w);
    o[4]=f2bf(b.x); o[5]=f2bf(b.y); o[6]=f2bf(b.z); o[7]=f2bf(b.w);
    ((u16x8*)out)[i] = o;
  }
}

__global__ __launch_bounds__(256) void cvt7(
    const float* __restrict__ s0, const float* __restrict__ s1,
    const float* __restrict__ s2, const float* __restrict__ s3,
    const float* __restrict__ s4, const float* __restrict__ s5,
    const float* __restrict__ s6,
    u16* __restrict__ d0, u16* __restrict__ d1, u16* __restrict__ d2,
    u16* __restrict__ d3, u16* __restrict__ d4, u16* __restrict__ d5,
    u16* __restrict__ d6) {
  const float* src; u16* dst; int n8;
  switch (blockIdx.y) {
    case 0: src = s0; dst = d0; n8 = 2097152; break;
    case 1: src = s1; dst = d1; n8 = 2097152; break;
    case 2: src = s2; dst = d2; n8 = 2097152; break;
    case 3: src = s3; dst = d3; n8 = 2097152; break;
    case 4: src = s4; dst = d4; n8 = 2097152; break;
    case 5: src = s5; dst = d5; n8 = 524288;  break;
    default: src = s6; dst = d6; n8 = 524288; break;
  }
  cvt_body(src, dst, n8);
}

#define MFMA_(A, B, C) __builtin_amdgcn_mfma_f32_16x16x32_bf16(A, B, C, 0, 0, 0)

// ---------------- 256x256 bf16 GEMM: ONE barrier per K-tile (r10/r12-validated) -----
// 512 thr = 8 waves (2M x 4N), per-wave 128x64, BK=64. A dbuf (64K), B tribuf (96K).
// COUNTED tile-end WAITVM(4) (T4): leaves B(kt+2)x4 in flight ACROSS the barrier.
// HAZARD SEAL (FIFO-traced r10, replay-clean r10/r12).
template<int OUTF32>
__device__ __forceinline__ void gemm256_body(
    const u16* __restrict__ Ag, const u16* __restrict__ Bg, void* __restrict__ Cp,
    const int K, const int ldc, const long m0, const long n0, const long cb,
    const float escale, u16* __restrict__ As, u16* __restrict__ Bs) {
  const int lane = threadIdx.x & 63, w = threadIdx.x >> 6;
  const int wm = w >> 2, wn = w & 3;
  const int c = lane & 15, grp = lane >> 4;
  const int lr = lane >> 3, lch = lane & 7;

  f32x4 acc[8][4] = {};
  const int NK = K >> 6;   // requires NK >= 3

  STG(Bg, n0, Bs, 0, 0, K);   STG(Bg, n0, Bs, 64, 0, K);
  STG(Bg, n0, Bs, 128, 0, K); STG(Bg, n0, Bs, 192, 0, K);
  STG(Ag, m0, As, 0, 0, K);   STG(Ag, m0, As, 64, 0, K);
  STG(Ag, m0, As, 128, 0, K); STG(Ag, m0, As, 192, 0, K);
  {
    u16* B1 = Bs + 16384;
    STG(Bg, n0, B1, 0, 1, K);   STG(Bg, n0, B1, 64, 1, K);
    STG(Bg, n0, B1, 128, 1, K); STG(Bg, n0, B1, 192, 1, K);
  }
  WAITVM(4);   // leaves [B(1)x4] — the loop invariant
  SBAR();

  for (int kt = 0; kt < NK; ++kt) {
    const u16* At = As + (kt & 1) * 16384;
    u16* An = As + ((kt & 1) ^ 1) * 16384;
    const u16* Bt = Bs + (kt % 3) * 16384;
    u16* Bn = Bs + ((kt + 2) % 3) * 16384;
    const bool am = (kt + 1 < NK), bm = (kt + 2 < NK);

    bf16x8 a0, a1, a2, a3, bfr[4];
#define LDAF(mi, ks) (*(const bf16x8*)(At + (wm*128 + (mi)*16 + c)*64 + ((((ks)*4 + grp)) ^ (c & 7))*8))
#define LDBF(ni, ks) (*(const bf16x8*)(Bt + (wn*64  + (ni)*16 + c)*64 + ((((ks)*4 + grp)) ^ (c & 7))*8))
#define MFMA16(MB) do { \
    __builtin_amdgcn_s_setprio(1); \
    _Pragma("unroll") \
    for (int ni = 0; ni < 4; ++ni) { \
      acc[(MB)+0][ni] = MFMA_(a0, bfr[ni], acc[(MB)+0][ni]); \
      acc[(MB)+1][ni] = MFMA_(a1, bfr[ni], acc[(MB)+1][ni]); \
      acc[(MB)+2][ni] = MFMA_(a2, bfr[ni], acc[(MB)+2][ni]); \
      acc[(MB)+3][ni] = MFMA_(a3, bfr[ni], acc[(MB)+3][ni]); \
    } \
    __builtin_amdgcn_s_setprio(0); } while (0)

    // phi0: mi0-3 x ks0  (+ stage A(kt+1) all 4 rounds)
    a0 = LDAF(0,0); a1 = LDAF(1,0); a2 = LDAF(2,0); a3 = LDAF(3,0);
    bfr[0] = LDBF(0,0); bfr[1] = LDBF(1,0); bfr[2] = LDBF(2,0); bfr[3] = LDBF(3,0);
    if (am) { STG(Ag, m0, An, 0, kt+1, K); STG(Ag, m0, An, 64, kt+1, K);
              STG(Ag, m0, An, 128, kt+1, K); STG(Ag, m0, An, 192, kt+1, K); }
    MFMA16(0);
    SCHEDB();
    // phi1: mi4-7 x ks0  (+ stage B(kt+2) r0,r64)
    a0 = LDAF(4,0); a1 = LDAF(5,0); a2 = LDAF(6,0); a3 = LDAF(7,0);
    if (bm) { STG(Bg, n0, Bn, 0, kt+2, K); STG(Bg, n0, Bn, 64, kt+2, K); }
    MFMA16(4);
    SCHEDB();
    // phi2: mi0-3 x ks1  (+ stage B(kt+2) r128,r192)
    a0 = LDAF(0,1); a1 = LDAF(1,1); a2 = LDAF(2,1); a3 = LDAF(3,1);
    bfr[0] = LDBF(0,1); bfr[1] = LDBF(1,1); bfr[2] = LDBF(2,1); bfr[3] = LDBF(3,1);
    if (bm) { STG(Bg, n0, Bn, 128, kt+2, K); STG(Bg, n0, Bn, 192, kt+2, K); }
    MFMA16(0);
    SCHEDB();
    // phi3: mi4-7 x ks1
    a0 = LDAF(4,1); a1 = LDAF(5,1); a2 = LDAF(6,1); a3 = LDAF(7,1);
    MFMA16(4);
    // tile boundary: counted drain (leaves B(kt+2)x4 in flight), single rendezvous
    if (bm) { WAITVM(4); } else { WAITVM(0); }
    SBAR();
    SCHEDB();
#undef MFMA16
#undef LDAF
#undef LDBF
  }

  // epilogue: C/D layout col = lane&15, row = (lane>>4)*4 + reg  [m89/m91]
  #pragma unroll
  for (int mi = 0; mi < 8; ++mi) {
    #pragma unroll
    for (int rr = 0; rr < 4; ++rr) {
      long row = m0 + wm*128 + mi*16 + grp*4 + rr;
      #pragma unroll
      for (int ni = 0; ni < 4; ++ni) {
        long col = cb + wn*64 + ni*16 + c;
        if (OUTF32) ((float*)Cp)[row*ldc + col] = acc[mi][ni][rr];
        else        ((u16*)Cp)[row*ldc + col]  = f2bf(acc[mi][ni][rr] * escale);
      }
    }
  }
}

// ---------------- 128x256 bf16 GEMM (KV half-job): r10 schedule + fused V^T out -----
// Counted WAITVM(6)/tile. VOUT=0: K-proj -> KVp[4096][1024]. VOUT=1: V-proj ->
// Vt[b][feat][s] transposed directly (u16x4; rr spans 4 consecutive s).
template<int VOUT>
__device__ __forceinline__ void gemm128_body(
    const u16* __restrict__ Ag, const u16* __restrict__ Bg, u16* __restrict__ Cp,
    u16* __restrict__ Vt, const int K, const int ldc, const long m0, const long n0,
    const long cb, u16* __restrict__ As, u16* __restrict__ Bs) {
  const int lane = threadIdx.x & 63, w = threadIdx.x >> 6;
  const int wm = w >> 2, wn = w & 3;
  const int c = lane & 15, grp = lane >> 4;
  const int lr = lane >> 3, lch = lane & 7;

  f32x4 acc[4][4] = {};
  const int NK = K >> 6;   // requires NK >= 3

  STG(Bg, n0, Bs, 0, 0, K);   STG(Bg, n0, Bs, 64, 0, K);
  STG(Bg, n0, Bs, 128, 0, K); STG(Bg, n0, Bs, 192, 0, K);
  STG(Ag, m0, As, 0, 0, K);   STG(Ag, m0, As, 64, 0, K);
  {
    u16* B1 = Bs + 16384; u16* A1 = As + 8192;
    STG(Bg, n0, B1, 0, 1, K);   STG(Bg, n0, B1, 64, 1, K);
    STG(Bg, n0, B1, 128, 1, K); STG(Bg, n0, B1, 192, 1, K);
    STG(Ag, m0, A1, 0, 1, K);   STG(Ag, m0, A1, 64, 1, K);
  }
  WAITVM(6);   // leaves [B(1)x4, A(1)x2] — the loop invariant
  SBAR();

  for (int kt = 0; kt < NK; ++kt) {
    const u16* At = As + (kt % 3) * 8192;
    const u16* Bt = Bs + (kt % 3) * 16384;
    u16* An = As + ((kt + 2) % 3) * 8192;
    u16* Bn = Bs + ((kt + 2) % 3) * 16384;
    const bool bm = (kt + 2 < NK);

    bf16x8 a0, a1, a2, a3, bfr[4];
#define LDAF(mi, ks) (*(const bf16x8*)(At + (wm*64 + (mi)*16 + c)*64 + ((((ks)*4 + grp)) ^ (c & 7))*8))
#define LDBF(ni, ks) (*(const bf16x8*)(Bt + (wn*64 + (ni)*16 + c)*64 + ((((ks)*4 + grp)) ^ (c & 7))*8))
#define MFMA16K() do { \
    __builtin_amdgcn_s_setprio(1); \
    _Pragma("unroll") \
    for (int ni = 0; ni < 4; ++ni) { \
      acc[0][ni] = MFMA_(a0, bfr[ni], acc[0][ni]); \
      acc[1][ni] = MFMA_(a1, bfr[ni], acc[1][ni]); \
      acc[2][ni] = MFMA_(a2, bfr[ni], acc[2][ni]); \
      acc[3][ni] = MFMA_(a3, bfr[ni], acc[3][ni]); \
    } \
    __builtin_amdgcn_s_setprio(0); } while (0)

    // phi0: ks0  (+ stage B(kt+2) r0,r64)
    a0 = LDAF(0,0); a1 = LDAF(1,0); a2 = LDAF(2,0); a3 = LDAF(3,0);
    bfr[0] = LDBF(0,0); bfr[1] = LDBF(1,0); bfr[2] = LDBF(2,0); bfr[3] = LDBF(3,0);
    if (bm) { STG(Bg, n0, Bn, 0, kt+2, K); STG(Bg, n0, Bn, 64, kt+2, K); }
    MFMA16K();
    SCHEDB();
    // phi1: ks1  (+ stage B(kt+2) r128,r192 + A(kt+2) x2)
    a0 = LDAF(0,1); a1 = LDAF(1,1); a2 = LDAF(2,1); a3 = LDAF(3,1);
    bfr[0] = LDBF(0,1); bfr[1] = LDBF(1,1); bfr[2] = LDBF(2,1); bfr[3] = LDBF(3,1);
    if (bm) { STG(Bg, n0, Bn, 128, kt+2, K); STG(Bg, n0, Bn, 192, kt+2, K);
              STG(Ag, m0, An, 0, kt+2, K); STG(Ag, m0, An, 64, kt+2, K); }
    MFMA16K();
    if (bm) { WAITVM(6); } else { WAITVM(0); }
    SBAR();
    SCHEDB();
#undef MFMA16K
#undef LDAF
#undef LDBF
  }

  if (VOUT == 0) {
    #pragma unroll
    for (int mi = 0; mi < 4; ++mi) {
      #pragma unroll
      for (int rr = 0; rr < 4; ++rr) {
        long row = m0 + wm*64 + mi*16 + grp*4 + rr;
        #pragma unroll
        for (int ni = 0; ni < 4; ++ni) {
          long col = cb + wn*64 + ni*16 + c;
          Cp[row*ldc + col] = f2bf(acc[mi][ni][rr]);
        }
      }
    }
  } else {
    // transposed write: Vt[b][feat][s], 4 consecutive s per u16x4 store
    #pragma unroll
    for (int mi = 0; mi < 4; ++mi) {
      long s_glob = m0 + wm*64 + mi*16 + grp*4;
      long bb = s_glob >> 11;
      long s_loc = s_glob & 2047;
      #pragma unroll
      for (int ni = 0; ni < 4; ++ni) {
        long feat = cb + wn*64 + ni*16 + c;
        u16x4 o4;
        #pragma unroll
        for (int rr = 0; rr < 4; ++rr) o4[rr] = f2bf(acc[mi][ni][rr]);
        *(u16x4*)(Vt + (bb*1024 + feat)*2048 + s_loc) = o4;
      }
    }
  }
}

// Balanced proj (re-fused, r12-validated): 256 blocks, Q tile + KV half-job each.
__global__ __launch_bounds__(512, 2) void proj_gemm(
    const u16* __restrict__ qb, const u16* __restrict__ kb,
    const u16* __restrict__ vb, const u16* __restrict__ wqb,
    const u16* __restrict__ wkv, u16* __restrict__ Qp, u16* __restrict__ KVp,
    u16* __restrict__ Vt) {
  __shared__ __attribute__((aligned(16))) u16 SMEM[81920];   // 160 KiB
  int wg = ((int)blockIdx.x & 7) * 32 + ((int)blockIdx.x >> 3);  // XCD swizzle
  gemm256_body<0>(qb, wqb, Qp, 4096, 4096,
                  (long)(wg >> 4) * 256, (long)(wg & 15) * 256, (long)(wg & 15) * 256,
                  SCL2E, SMEM, SMEM + 32768);
  {
    int mt = wg >> 3, nt = wg & 7;
    long n0 = (long)(nt & 3) * 256;
    if (nt < 4)
      gemm128_body<0>(kb, wkv, KVp, nullptr, 4096, 1024, (long)mt * 128, n0, n0,
                      SMEM, SMEM + 24576);
    else
      gemm128_body<1>(vb, wkv + 4194304, nullptr, Vt, 4096, 0, (long)mt * 128, n0, n0,
                      SMEM, SMEM + 24576);
  }
}

__global__ __launch_bounds__(512, 2) void gemm_out(
    const u16* __restrict__ A, const u16* __restrict__ Bw, float* __restrict__ C) {
  __shared__ __attribute__((aligned(16))) u16 SMEM[81920];   // 160 KiB
  int wg = ((int)blockIdx.x & 7) * 32 + ((int)blockIdx.x >> 3);  // 256%8==0
  long m0 = (long)(wg >> 4) * 256, n0 = (long)(wg & 15) * 256;
  gemm256_body<1>(A, Bw, C, 4096, 4096, m0, n0, n0, 1.f, SMEM, SMEM + 32768);
}

// ---------------- causal flash attention (r7 base + l-via-ones-MFMA r14) ----------
// 512-thread / 8-wave blocks, 256-row Q-tiles, paired (x, 7-x), 1 uniform round.
// NEW (r14): softmax denominator l computed by MFMA with ones A-operand
// (D[i][q] = sum_k P[k][q], accumulated in oaccL alongside oacc, rescaled by the
// same defer-max corr) — removes 32 v_add + 4 ds_bpermute serial chain per tile.
__global__ __launch_bounds__(512, 2) void attn_fwd(
    const u16* __restrict__ Qp, const u16* __restrict__ KVp,
    const u16* __restrict__ Vt, u16* __restrict__ AO) {
  const int head = blockIdx.y, b = blockIdx.z;
  const int g = head >> 2;
  const int tid = threadIdx.x, lane = tid & 63, w = tid >> 6;
  const int c = lane & 15, grp = lane >> 4;

  __shared__ __attribute__((aligned(16))) u16 Ks[2][64*128];
  __shared__ __attribute__((aligned(16))) u16 Vts[2][128*64];
  __shared__ __attribute__((aligned(16))) u16 Ps[8][32*64];
  u16* __restrict__ pw = &Ps[w][0];

  bf16x8 vones;
  #pragma unroll
  for (int j = 0; j < 8; ++j) vones[j] = (__bf16)1.0f;

  for (int half = 0; half < 2; ++half) {
    const int qt = half ? (7 - (int)blockIdx.x) : (int)blockIdx.x;
    const int q0 = qt * 256;
    const int qw = q0 + w * 32;

    bf16x8 qf[2][4];   // Q[qw + h*16 + c][t*32 + grp*8 + j]
    #pragma unroll
    for (int h = 0; h < 2; ++h) {
      const u16* qb = Qp + (long)(b*2048 + qw + h*16 + c)*4096 + head*128 + grp*8;
      #pragma unroll
      for (int t = 0; t < 4; ++t) qf[h][t] = *(const bf16x8*)(qb + t*32);
    }

    float m_run[2] = {-1e30f, -1e30f};
    f32x4 oacc[2][8] = {};
    f32x4 oaccL[2] = {};   // l accumulator: every element = running sum_k P

    const int ntiles = 4*qt + 4;

    auto STAGE = [&](int buf, int kt) {
      const int kv0 = kt * 64;
      #pragma unroll
      for (int p = 0; p < 2; ++p) {
        int idx = p*512 + w*64 + lane;
        int krow = idx >> 4, kc = idx & 15;
        int kcs = kc ^ (krow & 7);            // pre-swizzled source -> swizzled LDS
        gld16(KVp + (long)(b*2048 + kv0 + krow)*1024 + g*128 + kcs*8,
              &Ks[buf][(p*512 + w*64)*8]);
        int d = idx >> 3, vc = idx & 7;
        int vcs = vc ^ (d & 7);
        gld16(Vt + (long)(b*1024 + g*128 + d)*2048 + kv0 + vcs*8,
              &Vts[buf][(p*512 + w*64)*8]);
      }
    };

    if (half) __syncthreads();   // LDS reuse guard between q-tiles
    STAGE(0, 0);
    int cur = 0;
    for (int kt = 0; kt < ntiles; ++kt) {
      const int kv0 = kt * 64;
      __syncthreads();   // implicit vmcnt(0)+lgkmcnt(0) drain: buf[cur] ready
      if (kt + 1 < ntiles) STAGE(cur ^ 1, kt + 1);

      if (kv0 <= qw + 31) {   // wave-uniform: skip fully-masked tiles
        const u16* __restrict__ Kc = &Ks[cur][0];
        const u16* __restrict__ Vc = &Vts[cur][0];

        // S^T = mfma(K, Q): lane holds S[q=qw+h*16+c][kv0 + f*16 + grp*4 + r]
        f32x4 sacc[2][4] = {};
        __builtin_amdgcn_s_setprio(1);
        #pragma unroll
        for (int f = 0; f < 4; ++f) {
          const int row = f*16 + c;
          #pragma unroll
          for (int t = 0; t < 4; ++t) {
            bf16x8 kf = *(const bf16x8*)(Kc + row*128 + (((t*4 + grp) ^ (c & 7)) * 8));
            sacc[0][f] = __builtin_amdgcn_mfma_f32_16x16x32_bf16(kf, qf[0][t], sacc[0][f], 0, 0, 0);
            sacc[1][f] = __builtin_amdgcn_mfma_f32_16x16x32_bf16(kf, qf[1][t], sacc[1][f], 0, 0, 0);
          }
        }
        __builtin_amdgcn_s_setprio(0);

        #pragma unroll
        for (int h = 0; h < 2; ++h) {
          const int qg = qw + h*16 + c;
          float sv[16];
          if (kv0 + 63 > qw + h*16) {          // boundary tile for this fragment
            #pragma unroll
            for (int f = 0; f < 4; ++f)
              #pragma unroll
              for (int r = 0; r < 4; ++r) {
                float x = sacc[h][f][r];
                if (kv0 + f*16 + grp*4 + r > qg) x = -1e30f;
                sv[f*4 + r] = x;
              }
          } else {
            #pragma unroll
            for (int f = 0; f < 4; ++f)
              #pragma unroll
              for (int r = 0; r < 4; ++r) sv[f*4 + r] = sacc[h][f][r];
          }
          float tm[8];
          #pragma unroll
          for (int i = 0; i < 8; ++i) tm[i] = fmaxf(sv[i], sv[i+8]);
          #pragma unroll
          for (int i = 0; i < 4; ++i) tm[i] = fmaxf(tm[i], tm[i+4]);
          float tmax = fmaxf(fmaxf(tm[0], tm[2]), fmaxf(tm[1], tm[3]));
          tmax = fmaxf(tmax, __shfl_xor(tmax, 16));
          tmax = fmaxf(tmax, __shfl_xor(tmax, 32));

          float m_new = m_run[h];
          if (!__all(tmax <= m_run[h] + 8.f)) {   // defer-max
            m_new = fmaxf(m_run[h], tmax);
            float corr = exp2f(m_run[h] - m_new);
            #pragma unroll
            for (int n = 0; n < 8; ++n) oacc[h][n] *= corr;
            oaccL[h] *= corr;
            m_run[h] = m_new;
          }

          u32 pk[8];
          #pragma unroll
          for (int i = 0; i < 8; ++i) {
            float p0 = exp2f(sv[2*i]   - m_new);
            float p1 = exp2f(sv[2*i+1] - m_new);
            pk[i] = cvt_pk_bf16(p0, p1);
          }

          // P rows h*16+c, col swizzle ^= (q&7)<<3, packed b64 writes
          #pragma unroll
          for (int f = 0; f < 4; ++f) {
            int col = (f*16 + grp*4) ^ ((c & 7) << 3);
            u32x2 pv; pv[0] = pk[2*f]; pv[1] = pk[2*f + 1];
            *(u32x2*)(pw + (h*16 + c)*64 + col) = pv;
          }
        }

        // O^T += mfma(V^T, P^T); l += mfma(ones, P^T)  [all rows of D equal sum_k P]
        __builtin_amdgcn_s_setprio(1);
        #pragma unroll
        for (int u = 0; u < 2; ++u) {
          const int pcol = (u*32 + grp*8) ^ ((c & 7) << 3);
          bf16x8 pf0 = *(const bf16x8*)(pw + c*64 + pcol);
          bf16x8 pf1 = *(const bf16x8*)(pw + (16 + c)*64 + pcol);
          #pragma unroll
          for (int n = 0; n < 8; ++n) {
            bf16x8 vf = *(const bf16x8*)(Vc + (n*16 + c)*64 + (((u*4 + grp) ^ (c & 7)) * 8));
            oacc[0][n] = __builtin_amdgcn_mfma_f32_16x16x32_bf16(vf, pf0, oacc[0][n], 0, 0, 0);
            oacc[1][n] = __builtin_amdgcn_mfma_f32_16x16x32_bf16(vf, pf1, oacc[1][n], 0, 0, 0);
          }
          oaccL[0] = __builtin_amdgcn_mfma_f32_16x16x32_bf16(vones, pf0, oaccL[0], 0, 0, 0);
          oaccL[1] = __builtin_amdgcn_mfma_f32_16x16x32_bf16(vones, pf1, oaccL[1], 0, 0, 0);
        }
        __builtin_amdgcn_s_setprio(0);
      }
      cur ^= 1;
    }

    #pragma unroll
    for (int h = 0; h < 2; ++h) {
      const float inv = 1.0f / oaccL[h][0];
      u16* ob = AO + (long)(b*2048 + qw + h*16 + c)*4096 + head*128 + grp*4;
      #pragma unroll
      for (int n = 0; n < 8; ++n) {
        u32x2 o;
        o[0] = cvt_pk_bf16(oacc[h][n][0]*inv, oacc[h][n][1]*inv);
        o[1] = cvt_pk_bf16(oacc[h][n][2]*inv, oacc[h][n][3]*inv);
        *(u32x2*)(ob + n*16) = o;
      }
    }
  }
}

// ---------------- launcher ----------------
extern "C" void kernel_launch(void* const* d_in, const int* in_sizes, int n_in,
                              void* d_out, int out_size, void* d_ws, size_t ws_size,
                              hipStream_t stream) {
  const float* q   = (const float*)d_in[0];
  const float* k   = (const float*)d_in[1];
  const float* v   = (const float*)d_in[2];
  const float* w_q = (const float*)d_in[3];
  const float* w_k = (const float*)d_in[4];
  const float* w_v = (const float*)d_in[5];
  const float* w_o = (const float*)d_in[6];

  u16* ws  = (u16*)d_ws;
  u16* qb  = ws;                  // 16777216  q bf16
  u16* kb  = qb  + 16777216;      // 16777216  k bf16
  u16* vb  = kb  + 16777216;      // 16777216  v bf16
  u16* wqb = vb  + 16777216;      // 16777216  w_q bf16
  u16* wob = wqb + 16777216;      // 16777216  w_out bf16
  u16* wkv = wob + 16777216;      // 8388608   [w_k ; w_v] bf16
  u16* Qp  = wkv + 8388608;       // 16777216  query proj (pre-scaled by SCL2E)
  u16* KVp = Qp  + 16777216;      // 4194304   K proj [4096][1024]
  u16* Vtp = KVp + 4194304;       // 4194304   V^T [2][1024][2048] (direct from proj)
  u16* AO  = vb;                  // alias: vb dead after proj_gemm
  (void)ws_size; (void)in_sizes; (void)n_in; (void)out_size;

  // all 7 f32->bf16 conversions, one dispatch
  cvt7<<<dim3(1024, 7), dim3(256), 0, stream>>>(
      q, k, v, w_q, w_o, w_k, w_v,
      qb, kb, vb, wqb, wob, wkv, wkv + 4194304);

  // Q/K/V projections: 256 balanced blocks; V written transposed directly
  proj_gemm<<<256, dim3(512), 0, stream>>>(qb, kb, vb, wqb, wkv, Qp, KVp, Vtp);
  // flash attention: 256 uniform 8-wave blocks (paired 256-row q-tiles)
  attn_fwd<<<dim3(4,32,2), dim3(512), 0, stream>>>(Qp, KVp, Vtp, AO);
  // out = AO @ w_out^T : f32 -> d_out (256 blocks)
  gemm_out<<<256, dim3(512), 0, stream>>>(AO, wob, (float*)d_out);
}

// Round 15
// 515.431 us; speedup vs baseline: 1.0205x; 1.0035x over previous
//
#include <hip/hip_runtime.h>

typedef unsigned short u16;
typedef unsigned int u32;
typedef __bf16 bf16x8 __attribute__((ext_vector_type(8)));
typedef float f32x4 __attribute__((ext_vector_type(4)));
typedef u16 u16x4 __attribute__((ext_vector_type(4)));
typedef u16 u16x8 __attribute__((ext_vector_type(8)));
typedef u32 u32x2 __attribute__((ext_vector_type(2)));

#define SCL2E 0.12751744898229718f   // (1/sqrt(128)) * log2(e), folded into Q-proj

__device__ __forceinline__ u16 f2bf(float f) {
  union { float f; u32 u; } x; x.f = f;
  u32 r = x.u + 0x7fffu + ((x.u >> 16) & 1u);   // RNE
  return (u16)(r >> 16);
}

__device__ __forceinline__ u32 cvt_pk_bf16(float lo, float hi) {
  u32 r;
  asm("v_cvt_pk_bf16_f32 %0, %1, %2" : "=v"(r) : "v"(lo), "v"(hi));
  return r;
}

__device__ __forceinline__ void gld16(const void* g, void* l) {
  __builtin_amdgcn_global_load_lds(
      (const __attribute__((address_space(1))) u32*)g,
      (__attribute__((address_space(3))) u32*)l, 16, 0, 0);
}

#define SBAR() __builtin_amdgcn_s_barrier()
#define SCHEDB() __builtin_amdgcn_sched_barrier(0)
#define WAITVM(N) do { asm volatile("s_waitcnt vmcnt(" #N ")" ::: "memory"); \
                       __builtin_amdgcn_sched_barrier(0); } while (0)

// stage one 64-row round (1 gld_lds/thread): tile rows RIT..RIT+63, k-cols KT*64..+63
#define STG(G, R0, DST, RIT, KT, K) do { \
    int rit_ = (RIT) + w*8 + lr; \
    int ch_ = lch ^ (rit_ & 7); \
    gld16((G) + ((R0) + rit_) * (long)(K) + (long)(KT)*64 + ch_*8, \
          (DST) + ((RIT) + w*8)*64); } while (0)

// ---------------- fp32 -> bf16 convert: ALL 7 tensors in one dispatch ----------------
__device__ __forceinline__ void cvt_body(const float* __restrict__ in,
                                         u16* __restrict__ out, int n8) {
  int stride = gridDim.x * 256;
  for (int i = blockIdx.x * 256 + threadIdx.x; i < n8; i += stride) {
    float4 a = ((const float4*)in)[2*i];
    float4 b = ((const float4*)in)[2*i+1];
    u16x8 o;
    o[0]=f2bf(a.x); o[1]=f2bf(a.y); o[2]=f2bf(a.z); o[3]=f2bf(a.w);
    o[4]=f2bf(b.x); o[5]=f2bf(b.y); o[6]=f2bf(b.z); o[7]=f2bf(b.w);
    ((u16x8*)out)[i] = o;
  }
}

__global__ __launch_bounds__(256) void cvt7(
    const float* __restrict__ s0, const float* __restrict__ s1,
    const float* __restrict__ s2, const float* __restrict__ s3,
    const float* __restrict__ s4, const float* __restrict__ s5,
    const float* __restrict__ s6,
    u16* __restrict__ d0, u16* __restrict__ d1, u16* __restrict__ d2,
    u16* __restrict__ d3, u16* __restrict__ d4, u16* __restrict__ d5,
    u16* __restrict__ d6) {
  const float* src; u16* dst; int n8;
  switch (blockIdx.y) {
    case 0: src = s0; dst = d0; n8 = 2097152; break;
    case 1: src = s1; dst = d1; n8 = 2097152; break;
    case 2: src = s2; dst = d2; n8 = 2097152; break;
    case 3: src = s3; dst = d3; n8 = 2097152; break;
    case 4: src = s4; dst = d4; n8 = 2097152; break;
    case 5: src = s5; dst = d5; n8 = 524288;  break;
    default: src = s6; dst = d6; n8 = 524288; break;
  }
  cvt_body(src, dst, n8);
}

#define MFMA_(A, B, C) __builtin_amdgcn_mfma_f32_16x16x32_bf16(A, B, C, 0, 0, 0)

// ---------------- 256x256 bf16 GEMM: ONE barrier per K-tile (r10/r12-validated) -----
// 512 thr = 8 waves (2M x 4N), per-wave 128x64, BK=64. A dbuf (64K), B tribuf (96K).
// COUNTED tile-end WAITVM(4) (T4): leaves B(kt+2)x4 in flight ACROSS the barrier.
// HAZARD SEAL (FIFO-traced r10, replay-clean r10/r12/r14).
template<int OUTF32>
__device__ __forceinline__ void gemm256_body(
    const u16* __restrict__ Ag, const u16* __restrict__ Bg, void* __restrict__ Cp,
    const int K, const int ldc, const long m0, const long n0, const long cb,
    const float escale, u16* __restrict__ As, u16* __restrict__ Bs) {
  const int lane = threadIdx.x & 63, w = threadIdx.x >> 6;
  const int wm = w >> 2, wn = w & 3;
  const int c = lane & 15, grp = lane >> 4;
  const int lr = lane >> 3, lch = lane & 7;

  f32x4 acc[8][4] = {};
  const int NK = K >> 6;   // requires NK >= 3

  STG(Bg, n0, Bs, 0, 0, K);   STG(Bg, n0, Bs, 64, 0, K);
  STG(Bg, n0, Bs, 128, 0, K); STG(Bg, n0, Bs, 192, 0, K);
  STG(Ag, m0, As, 0, 0, K);   STG(Ag, m0, As, 64, 0, K);
  STG(Ag, m0, As, 128, 0, K); STG(Ag, m0, As, 192, 0, K);
  {
    u16* B1 = Bs + 16384;
    STG(Bg, n0, B1, 0, 1, K);   STG(Bg, n0, B1, 64, 1, K);
    STG(Bg, n0, B1, 128, 1, K); STG(Bg, n0, B1, 192, 1, K);
  }
  WAITVM(4);   // leaves [B(1)x4] — the loop invariant
  SBAR();

  for (int kt = 0; kt < NK; ++kt) {
    const u16* At = As + (kt & 1) * 16384;
    u16* An = As + ((kt & 1) ^ 1) * 16384;
    const u16* Bt = Bs + (kt % 3) * 16384;
    u16* Bn = Bs + ((kt + 2) % 3) * 16384;
    const bool am = (kt + 1 < NK), bm = (kt + 2 < NK);

    bf16x8 a0, a1, a2, a3, bfr[4];
#define LDAF(mi, ks) (*(const bf16x8*)(At + (wm*128 + (mi)*16 + c)*64 + ((((ks)*4 + grp)) ^ (c & 7))*8))
#define LDBF(ni, ks) (*(const bf16x8*)(Bt + (wn*64  + (ni)*16 + c)*64 + ((((ks)*4 + grp)) ^ (c & 7))*8))
#define MFMA16(MB) do { \
    __builtin_amdgcn_s_setprio(1); \
    _Pragma("unroll") \
    for (int ni = 0; ni < 4; ++ni) { \
      acc[(MB)+0][ni] = MFMA_(a0, bfr[ni], acc[(MB)+0][ni]); \
      acc[(MB)+1][ni] = MFMA_(a1, bfr[ni], acc[(MB)+1][ni]); \
      acc[(MB)+2][ni] = MFMA_(a2, bfr[ni], acc[(MB)+2][ni]); \
      acc[(MB)+3][ni] = MFMA_(a3, bfr[ni], acc[(MB)+3][ni]); \
    } \
    __builtin_amdgcn_s_setprio(0); } while (0)

    // phi0: mi0-3 x ks0  (+ stage A(kt+1) all 4 rounds)
    a0 = LDAF(0,0); a1 = LDAF(1,0); a2 = LDAF(2,0); a3 = LDAF(3,0);
    bfr[0] = LDBF(0,0); bfr[1] = LDBF(1,0); bfr[2] = LDBF(2,0); bfr[3] = LDBF(3,0);
    if (am) { STG(Ag, m0, An, 0, kt+1, K); STG(Ag, m0, An, 64, kt+1, K);
              STG(Ag, m0, An, 128, kt+1, K); STG(Ag, m0, An, 192, kt+1, K); }
    MFMA16(0);
    SCHEDB();
    // phi1: mi4-7 x ks0  (+ stage B(kt+2) r0,r64)
    a0 = LDAF(4,0); a1 = LDAF(5,0); a2 = LDAF(6,0); a3 = LDAF(7,0);
    if (bm) { STG(Bg, n0, Bn, 0, kt+2, K); STG(Bg, n0, Bn, 64, kt+2, K); }
    MFMA16(4);
    SCHEDB();
    // phi2: mi0-3 x ks1  (+ stage B(kt+2) r128,r192)
    a0 = LDAF(0,1); a1 = LDAF(1,1); a2 = LDAF(2,1); a3 = LDAF(3,1);
    bfr[0] = LDBF(0,1); bfr[1] = LDBF(1,1); bfr[2] = LDBF(2,1); bfr[3] = LDBF(3,1);
    if (bm) { STG(Bg, n0, Bn, 128, kt+2, K); STG(Bg, n0, Bn, 192, kt+2, K); }
    MFMA16(0);
    SCHEDB();
    // phi3: mi4-7 x ks1
    a0 = LDAF(4,1); a1 = LDAF(5,1); a2 = LDAF(6,1); a3 = LDAF(7,1);
    MFMA16(4);
    // tile boundary: counted drain (leaves B(kt+2)x4 in flight), single rendezvous
    if (bm) { WAITVM(4); } else { WAITVM(0); }
    SBAR();
    SCHEDB();
#undef MFMA16
#undef LDAF
#undef LDBF
  }

  // epilogue: C/D layout col = lane&15, row = (lane>>4)*4 + reg  [m89/m91]
  #pragma unroll
  for (int mi = 0; mi < 8; ++mi) {
    #pragma unroll
    for (int rr = 0; rr < 4; ++rr) {
      long row = m0 + wm*128 + mi*16 + grp*4 + rr;
      #pragma unroll
      for (int ni = 0; ni < 4; ++ni) {
        long col = cb + wn*64 + ni*16 + c;
        if (OUTF32) ((float*)Cp)[row*ldc + col] = acc[mi][ni][rr];
        else        ((u16*)Cp)[row*ldc + col]  = f2bf(acc[mi][ni][rr] * escale);
      }
    }
  }
}

// ---------------- 128x256 bf16 GEMM (KV half-job): r10 schedule + fused V^T out -----
// Counted WAITVM(6)/tile. VOUT=0: K-proj -> KVp[4096][1024]. VOUT=1: V-proj ->
// Vt[b][feat][s] transposed directly (u16x4; rr spans 4 consecutive s).
template<int VOUT>
__device__ __forceinline__ void gemm128_body(
    const u16* __restrict__ Ag, const u16* __restrict__ Bg, u16* __restrict__ Cp,
    u16* __restrict__ Vt, const int K, const int ldc, const long m0, const long n0,
    const long cb, u16* __restrict__ As, u16* __restrict__ Bs) {
  const int lane = threadIdx.x & 63, w = threadIdx.x >> 6;
  const int wm = w >> 2, wn = w & 3;
  const int c = lane & 15, grp = lane >> 4;
  const int lr = lane >> 3, lch = lane & 7;

  f32x4 acc[4][4] = {};
  const int NK = K >> 6;   // requires NK >= 3

  STG(Bg, n0, Bs, 0, 0, K);   STG(Bg, n0, Bs, 64, 0, K);
  STG(Bg, n0, Bs, 128, 0, K); STG(Bg, n0, Bs, 192, 0, K);
  STG(Ag, m0, As, 0, 0, K);   STG(Ag, m0, As, 64, 0, K);
  {
    u16* B1 = Bs + 16384; u16* A1 = As + 8192;
    STG(Bg, n0, B1, 0, 1, K);   STG(Bg, n0, B1, 64, 1, K);
    STG(Bg, n0, B1, 128, 1, K); STG(Bg, n0, B1, 192, 1, K);
    STG(Ag, m0, A1, 0, 1, K);   STG(Ag, m0, A1, 64, 1, K);
  }
  WAITVM(6);   // leaves [B(1)x4, A(1)x2] — the loop invariant
  SBAR();

  for (int kt = 0; kt < NK; ++kt) {
    const u16* At = As + (kt % 3) * 8192;
    const u16* Bt = Bs + (kt % 3) * 16384;
    u16* An = As + ((kt + 2) % 3) * 8192;
    u16* Bn = Bs + ((kt + 2) % 3) * 16384;
    const bool bm = (kt + 2 < NK);

    bf16x8 a0, a1, a2, a3, bfr[4];
#define LDAF(mi, ks) (*(const bf16x8*)(At + (wm*64 + (mi)*16 + c)*64 + ((((ks)*4 + grp)) ^ (c & 7))*8))
#define LDBF(ni, ks) (*(const bf16x8*)(Bt + (wn*64 + (ni)*16 + c)*64 + ((((ks)*4 + grp)) ^ (c & 7))*8))
#define MFMA16K() do { \
    __builtin_amdgcn_s_setprio(1); \
    _Pragma("unroll") \
    for (int ni = 0; ni < 4; ++ni) { \
      acc[0][ni] = MFMA_(a0, bfr[ni], acc[0][ni]); \
      acc[1][ni] = MFMA_(a1, bfr[ni], acc[1][ni]); \
      acc[2][ni] = MFMA_(a2, bfr[ni], acc[2][ni]); \
      acc[3][ni] = MFMA_(a3, bfr[ni], acc[3][ni]); \
    } \
    __builtin_amdgcn_s_setprio(0); } while (0)

    // phi0: ks0  (+ stage B(kt+2) r0,r64)
    a0 = LDAF(0,0); a1 = LDAF(1,0); a2 = LDAF(2,0); a3 = LDAF(3,0);
    bfr[0] = LDBF(0,0); bfr[1] = LDBF(1,0); bfr[2] = LDBF(2,0); bfr[3] = LDBF(3,0);
    if (bm) { STG(Bg, n0, Bn, 0, kt+2, K); STG(Bg, n0, Bn, 64, kt+2, K); }
    MFMA16K();
    SCHEDB();
    // phi1: ks1  (+ stage B(kt+2) r128,r192 + A(kt+2) x2)
    a0 = LDAF(0,1); a1 = LDAF(1,1); a2 = LDAF(2,1); a3 = LDAF(3,1);
    bfr[0] = LDBF(0,1); bfr[1] = LDBF(1,1); bfr[2] = LDBF(2,1); bfr[3] = LDBF(3,1);
    if (bm) { STG(Bg, n0, Bn, 128, kt+2, K); STG(Bg, n0, Bn, 192, kt+2, K);
              STG(Ag, m0, An, 0, kt+2, K); STG(Ag, m0, An, 64, kt+2, K); }
    MFMA16K();
    if (bm) { WAITVM(6); } else { WAITVM(0); }
    SBAR();
    SCHEDB();
#undef MFMA16K
#undef LDAF
#undef LDBF
  }

  if (VOUT == 0) {
    #pragma unroll
    for (int mi = 0; mi < 4; ++mi) {
      #pragma unroll
      for (int rr = 0; rr < 4; ++rr) {
        long row = m0 + wm*64 + mi*16 + grp*4 + rr;
        #pragma unroll
        for (int ni = 0; ni < 4; ++ni) {
          long col = cb + wn*64 + ni*16 + c;
          Cp[row*ldc + col] = f2bf(acc[mi][ni][rr]);
        }
      }
    }
  } else {
    // transposed write: Vt[b][feat][s], 4 consecutive s per u16x4 store
    #pragma unroll
    for (int mi = 0; mi < 4; ++mi) {
      long s_glob = m0 + wm*64 + mi*16 + grp*4;
      long bb = s_glob >> 11;
      long s_loc = s_glob & 2047;
      #pragma unroll
      for (int ni = 0; ni < 4; ++ni) {
        long feat = cb + wn*64 + ni*16 + c;
        u16x4 o4;
        #pragma unroll
        for (int rr = 0; rr < 4; ++rr) o4[rr] = f2bf(acc[mi][ni][rr]);
        *(u16x4*)(Vt + (bb*1024 + feat)*2048 + s_loc) = o4;
      }
    }
  }
}

// Balanced proj (r12-validated): 256 blocks, Q tile + KV half-job each.
__global__ __launch_bounds__(512, 2) void proj_gemm(
    const u16* __restrict__ qb, const u16* __restrict__ kb,
    const u16* __restrict__ vb, const u16* __restrict__ wqb,
    const u16* __restrict__ wkv, u16* __restrict__ Qp, u16* __restrict__ KVp,
    u16* __restrict__ Vt) {
  __shared__ __attribute__((aligned(16))) u16 SMEM[81920];   // 160 KiB
  int wg = ((int)blockIdx.x & 7) * 32 + ((int)blockIdx.x >> 3);  // XCD swizzle
  gemm256_body<0>(qb, wqb, Qp, 4096, 4096,
                  (long)(wg >> 4) * 256, (long)(wg & 15) * 256, (long)(wg & 15) * 256,
                  SCL2E, SMEM, SMEM + 32768);
  {
    int mt = wg >> 3, nt = wg & 7;
    long n0 = (long)(nt & 3) * 256;
    if (nt < 4)
      gemm128_body<0>(kb, wkv, KVp, nullptr, 4096, 1024, (long)mt * 128, n0, n0,
                      SMEM, SMEM + 24576);
    else
      gemm128_body<1>(vb, wkv + 4194304, nullptr, Vt, 4096, 0, (long)mt * 128, n0, n0,
                      SMEM, SMEM + 24576);
  }
}

__global__ __launch_bounds__(512, 2) void gemm_out(
    const u16* __restrict__ A, const u16* __restrict__ Bw, float* __restrict__ C) {
  __shared__ __attribute__((aligned(16))) u16 SMEM[81920];   // 160 KiB
  int wg = ((int)blockIdx.x & 7) * 32 + ((int)blockIdx.x >> 3);  // 256%8==0
  long m0 = (long)(wg >> 4) * 256, n0 = (long)(wg & 15) * 256;
  gemm256_body<1>(A, Bw, C, 4096, 4096, m0, n0, n0, 1.f, SMEM, SMEM + 32768);
}

// ---------------- causal flash attention (r14 base + softmax/PV interleave r15) -----
// 512-thread / 8-wave blocks, 256-row Q-tiles, paired (x, 7-x), 1 uniform round.
// r15: per tile, softmax(h1) is computed BETWEEN the h0 and h1 PV MFMA clusters
// (u0 V-fragments held in regs, so V LDS-read count unchanged) — h1's VALU/trans
// chain co-issues under the h0 PV MFMA shadow and vice versa (T15 mechanism).
__global__ __launch_bounds__(512, 2) void attn_fwd(
    const u16* __restrict__ Qp, const u16* __restrict__ KVp,
    const u16* __restrict__ Vt, u16* __restrict__ AO) {
  const int head = blockIdx.y, b = blockIdx.z;
  const int g = head >> 2;
  const int tid = threadIdx.x, lane = tid & 63, w = tid >> 6;
  const int c = lane & 15, grp = lane >> 4;

  __shared__ __attribute__((aligned(16))) u16 Ks[2][64*128];
  __shared__ __attribute__((aligned(16))) u16 Vts[2][128*64];
  __shared__ __attribute__((aligned(16))) u16 Ps[8][32*64];
  u16* __restrict__ pw = &Ps[w][0];

  bf16x8 vones;
  #pragma unroll
  for (int j = 0; j < 8; ++j) vones[j] = (__bf16)1.0f;

  for (int half = 0; half < 2; ++half) {
    const int qt = half ? (7 - (int)blockIdx.x) : (int)blockIdx.x;
    const int q0 = qt * 256;
    const int qw = q0 + w * 32;

    bf16x8 qf[2][4];   // Q[qw + h*16 + c][t*32 + grp*8 + j]
    #pragma unroll
    for (int h = 0; h < 2; ++h) {
      const u16* qb = Qp + (long)(b*2048 + qw + h*16 + c)*4096 + head*128 + grp*8;
      #pragma unroll
      for (int t = 0; t < 4; ++t) qf[h][t] = *(const bf16x8*)(qb + t*32);
    }

    float m_run[2] = {-1e30f, -1e30f};
    f32x4 oacc[2][8] = {};
    f32x4 oaccL[2] = {};   // l accumulator via ones-MFMA (r14)

    const int ntiles = 4*qt + 4;

    auto STAGE = [&](int buf, int kt) {
      const int kv0 = kt * 64;
      #pragma unroll
      for (int p = 0; p < 2; ++p) {
        int idx = p*512 + w*64 + lane;
        int krow = idx >> 4, kc = idx & 15;
        int kcs = kc ^ (krow & 7);            // pre-swizzled source -> swizzled LDS
        gld16(KVp + (long)(b*2048 + kv0 + krow)*1024 + g*128 + kcs*8,
              &Ks[buf][(p*512 + w*64)*8]);
        int d = idx >> 3, vc = idx & 7;
        int vcs = vc ^ (d & 7);
        gld16(Vt + (long)(b*1024 + g*128 + d)*2048 + kv0 + vcs*8,
              &Vts[buf][(p*512 + w*64)*8]);
      }
    };

    // softmax for one 16-row fragment: mask, max-tree, defer-max rescale, exp,
    // pack to bf16, write P rows (qrow0-qw)+c to per-wave LDS.
    auto SOFTMAX_H = [&](f32x4 (&sc)[4], float& mr, f32x4 (&oa)[8], f32x4& oL,
                         const int qrow0, const int kv0) {
      const int qg = qrow0 + c;
      float sv[16];
      if (kv0 + 63 > qrow0) {
        #pragma unroll
        for (int f = 0; f < 4; ++f)
          #pragma unroll
          for (int r = 0; r < 4; ++r) {
            float x = sc[f][r];
            if (kv0 + f*16 + grp*4 + r > qg) x = -1e30f;
            sv[f*4 + r] = x;
          }
      } else {
        #pragma unroll
        for (int f = 0; f < 4; ++f)
          #pragma unroll
          for (int r = 0; r < 4; ++r) sv[f*4 + r] = sc[f][r];
      }
      float tm[8];
      #pragma unroll
      for (int i = 0; i < 8; ++i) tm[i] = fmaxf(sv[i], sv[i+8]);
      #pragma unroll
      for (int i = 0; i < 4; ++i) tm[i] = fmaxf(tm[i], tm[i+4]);
      float tmax = fmaxf(fmaxf(tm[0], tm[2]), fmaxf(tm[1], tm[3]));
      tmax = fmaxf(tmax, __shfl_xor(tmax, 16));
      tmax = fmaxf(tmax, __shfl_xor(tmax, 32));

      if (!__all(tmax <= mr + 8.f)) {   // defer-max
        float m_new = fmaxf(mr, tmax);
        float corr = exp2f(mr - m_new);
        #pragma unroll
        for (int n = 0; n < 8; ++n) oa[n] *= corr;
        oL *= corr;
        mr = m_new;
      }
      u32 pk[8];
      #pragma unroll
      for (int i = 0; i < 8; ++i) {
        float p0 = exp2f(sv[2*i]   - mr);
        float p1 = exp2f(sv[2*i+1] - mr);
        pk[i] = cvt_pk_bf16(p0, p1);
      }
      const int prow = qrow0 - qw + c;
      #pragma unroll
      for (int f = 0; f < 4; ++f) {
        int col = (f*16 + grp*4) ^ ((c & 7) << 3);
        u32x2 pv; pv[0] = pk[2*f]; pv[1] = pk[2*f + 1];
        *(u32x2*)(pw + prow*64 + col) = pv;
      }
    };

    if (half) __syncthreads();   // LDS reuse guard between q-tiles
    STAGE(0, 0);
    int cur = 0;
    for (int kt = 0; kt < ntiles; ++kt) {
      const int kv0 = kt * 64;
      __syncthreads();   // implicit vmcnt(0)+lgkmcnt(0) drain: buf[cur] ready
      if (kt + 1 < ntiles) STAGE(cur ^ 1, kt + 1);

      if (kv0 <= qw + 31) {   // wave-uniform: skip fully-masked tiles
        const u16* __restrict__ Kc = &Ks[cur][0];
        const u16* __restrict__ Vc = &Vts[cur][0];

        // S^T = mfma(K, Q): lane holds S[q=qw+h*16+c][kv0 + f*16 + grp*4 + r]
        f32x4 sacc[2][4] = {};
        __builtin_amdgcn_s_setprio(1);
        #pragma unroll
        for (int f = 0; f < 4; ++f) {
          const int row = f*16 + c;
          #pragma unroll
          for (int t = 0; t < 4; ++t) {
            bf16x8 kf = *(const bf16x8*)(Kc + row*128 + (((t*4 + grp) ^ (c & 7)) * 8));
            sacc[0][f] = MFMA_(kf, qf[0][t], sacc[0][f]);
            sacc[1][f] = MFMA_(kf, qf[1][t], sacc[1][f]);
          }
        }
        __builtin_amdgcn_s_setprio(0);

        const int pcol0 = (grp*8) ^ ((c & 7) << 3);        // u=0 P columns
        const int pcol1 = (32 + grp*8) ^ ((c & 7) << 3);   // u=1 P columns

        // ---- softmax h0, write P rows c ----
        SOFTMAX_H(sacc[0], m_run[0], oacc[0], oaccL[0], qw, kv0);

        // ---- PV h0/u0 (V u0 fragments held in regs for h1 reuse) ----
        bf16x8 vfr[8];
        #pragma unroll
        for (int n = 0; n < 8; ++n)
          vfr[n] = *(const bf16x8*)(Vc + (n*16 + c)*64 + ((grp ^ (c & 7)) * 8));
        {
          bf16x8 pf00 = *(const bf16x8*)(pw + c*64 + pcol0);
          #pragma unroll
          for (int n = 0; n < 8; ++n)
            oacc[0][n] = MFMA_(vfr[n], pf00, oacc[0][n]);
          oaccL[0] = MFMA_(vones, pf00, oaccL[0]);
        }

        // ---- softmax h1 (VALU/trans; co-issues under PV-h0 MFMA shadow) ----
        SOFTMAX_H(sacc[1], m_run[1], oacc[1], oaccL[1], qw + 16, kv0);

        // ---- PV h1/u0 from register V fragments ----
        {
          bf16x8 pf10 = *(const bf16x8*)(pw + (16 + c)*64 + pcol0);
          #pragma unroll
          for (int n = 0; n < 8; ++n)
            oacc[1][n] = MFMA_(vfr[n], pf10, oacc[1][n]);
          oaccL[1] = MFMA_(vones, pf10, oaccL[1]);
        }

        // ---- PV u1, both h ----
        __builtin_amdgcn_s_setprio(1);
        {
          bf16x8 pf01 = *(const bf16x8*)(pw + c*64 + pcol1);
          bf16x8 pf11 = *(const bf16x8*)(pw + (16 + c)*64 + pcol1);
          #pragma unroll
          for (int n = 0; n < 8; ++n) {
            bf16x8 vf = *(const bf16x8*)(Vc + (n*16 + c)*64 + (((4 + grp) ^ (c & 7)) * 8));
            oacc[0][n] = MFMA_(vf, pf01, oacc[0][n]);
            oacc[1][n] = MFMA_(vf, pf11, oacc[1][n]);
          }
          oaccL[0] = MFMA_(vones, pf01, oaccL[0]);
          oaccL[1] = MFMA_(vones, pf11, oaccL[1]);
        }
        __builtin_amdgcn_s_setprio(0);
      }
      cur ^= 1;
    }

    #pragma unroll
    for (int h = 0; h < 2; ++h) {
      const float inv = 1.0f / oaccL[h][0];
      u16* ob = AO + (long)(b*2048 + qw + h*16 + c)*4096 + head*128 + grp*4;
      #pragma unroll
      for (int n = 0; n < 8; ++n) {
        u32x2 o;
        o[0] = cvt_pk_bf16(oacc[h][n][0]*inv, oacc[h][n][1]*inv);
        o[1] = cvt_pk_bf16(oacc[h][n][2]*inv, oacc[h][n][3]*inv);
        *(u32x2*)(ob + n*16) = o;
      }
    }
  }
}

// ---------------- launcher ----------------
extern "C" void kernel_launch(void* const* d_in, const int* in_sizes, int n_in,
                              void* d_out, int out_size, void* d_ws, size_t ws_size,
                              hipStream_t stream) {
  const float* q   = (const float*)d_in[0];
  const float* k   = (const float*)d_in[1];
  const float* v   = (const float*)d_in[2];
  const float* w_q = (const float*)d_in[3];
  const float* w_k = (const float*)d_in[4];
  const float* w_v = (const float*)d_in[5];
  const float* w_o = (const float*)d_in[6];

  u16* ws  = (u16*)d_ws;
  u16* qb  = ws;                  // 16777216  q bf16
  u16* kb  = qb  + 16777216;      // 16777216  k bf16
  u16* vb  = kb  + 16777216;      // 16777216  v bf16
  u16* wqb = vb  + 16777216;      // 16777216  w_q bf16
  u16* wob = wqb + 16777216;      // 16777216  w_out bf16
  u16* wkv = wob + 16777216;      // 8388608   [w_k ; w_v] bf16
  u16* Qp  = wkv + 8388608;       // 16777216  query proj (pre-scaled by SCL2E)
  u16* KVp = Qp  + 16777216;      // 4194304   K proj [4096][1024]
  u16* Vtp = KVp + 4194304;       // 4194304   V^T [2][1024][2048] (direct from proj)
  u16* AO  = vb;                  // alias: vb dead after proj_gemm
  (void)ws_size; (void)in_sizes; (void)n_in; (void)out_size;

  // all 7 f32->bf16 conversions, one dispatch
  cvt7<<<dim3(1024, 7), dim3(256), 0, stream>>>(
      q, k, v, w_q, w_o, w_k, w_v,
      qb, kb, vb, wqb, wob, wkv, wkv + 4194304);

  // Q/K/V projections: 256 balanced blocks; V written transposed directly
  proj_gemm<<<256, dim3(512), 0, stream>>>(qb, kb, vb, wqb, wkv, Qp, KVp, Vtp);
  // flash attention: 256 uniform 8-wave blocks (paired 256-row q-tiles)
  attn_fwd<<<dim3(4,32,2), dim3(512), 0, stream>>>(Qp, KVp, Vtp, AO);
  // out = AO @ w_out^T : f32 -> d_out (256 blocks)
  gemm_out<<<256, dim3(512), 0, stream>>>(AO, wob, (float*)d_out);
}